// Round 9
// baseline (65.317 us; speedup 1.0000x reference)
//
#include <hip/hip_runtime.h>
#include <hip/hip_bf16.h>

#define BB 4
#define NN 512
#define EE 256
#define HH 8
#define DD 32
#define SCALING 0.17677669529663687f  // 32^-0.5
#define PR 8   // rows per proj block
#define RR 4   // rows per attn block

// ---------------------------------------------------------------------------
// Projection, one W per block (blockIdx.y: 0=Q,1=K,2=V).  Q pre-scaled
// [b,n,e]; K transposed Kt[((b*H+h)*D+d)*N+n] (coalesced reads in attn);
// V folded against Wf1/2/3 -> vw[((b*H+h)*3+c)*N+m].  768 blocks.
// ---------------------------------------------------------------------------
__global__ __launch_bounds__(256) void proj_kernel(
    const float* __restrict__ query,
    const float* __restrict__ Wq, const float* __restrict__ bq,
    const float* __restrict__ Wk, const float* __restrict__ bk,
    const float* __restrict__ Wv, const float* __restrict__ bv,
    const float* __restrict__ Wf1, const float* __restrict__ Wf2,
    const float* __restrict__ Wf3,
    float* __restrict__ Q, float* __restrict__ Kt, float* __restrict__ vw)
{
    __shared__ alignas(16) float s[PR][EE];    // 8 KB
    __shared__ alignas(16) float sv[PR][EE];   // 8 KB (V blocks only)
    const int which = blockIdx.y;
    const int row0 = blockIdx.x * PR;
    const int tid = threadIdx.x;               // output column e

    {
        const float4* src = (const float4*)(query + row0 * EE);
        ((float4*)s)[tid]       = src[tid];
        ((float4*)s)[tid + 256] = src[tid + 256];
    }
    __syncthreads();

    const float* W  = (which == 0) ? Wq : (which == 1) ? Wk : Wv;
    const float* bb = (which == 0) ? bq : (which == 1) ? bk : bv;

    float acc[PR];
    #pragma unroll
    for (int r = 0; r < PR; ++r) acc[r] = 0.f;

    const float4* W4 = (const float4*)(W + tid * EE);
    for (int j = 0; j < EE / 4; ++j) {
        const float4 w = W4[j];
        #pragma unroll
        for (int r = 0; r < PR; ++r) {
            const float4 x = *(const float4*)&s[r][4 * j];
            acc[r] += x.x * w.x + x.y * w.y + x.z * w.z + x.w * w.w;
        }
    }
    const float bbv = bb[tid];

    if (which == 0) {
        #pragma unroll
        for (int r = 0; r < PR; ++r)
            Q[(row0 + r) * EE + tid] = (acc[r] + bbv) * SCALING;
    } else if (which == 1) {
        const int h = tid >> 5, d = tid & 31;
        #pragma unroll
        for (int r = 0; r < PR; ++r) {
            const int grow = row0 + r;
            const int b = grow >> 9, n = grow & 511;
            Kt[((size_t)(b * HH + h) * DD + d) * NN + n] = acc[r] + bbv;
        }
    } else {
        #pragma unroll
        for (int r = 0; r < PR; ++r) sv[r][tid] = acc[r] + bbv;
        __syncthreads();
        if (tid < PR * 24) {                   // 192 threads: (r, h, c)
            const int r = tid / 24;
            const int rem = tid % 24;
            const int hh = rem / 3;
            const int c = rem % 3;
            const float* Wf = (c == 0) ? Wf1 : (c == 1) ? Wf2 : Wf3;
            float a = 0.f;
            #pragma unroll
            for (int dd = 0; dd < DD; ++dd)
                a += sv[r][hh * DD + dd] * Wf[hh * DD + dd];
            const int grow = row0 + r;
            const int b = grow >> 9, m = grow & 511;
            vw[((b * HH + hh) * 3 + c) * NN + m] = a;
        }
    }
}

// ---------------------------------------------------------------------------
// Fused attention: per block (b, 4 rows), thread = column m.
//   P1: for all 8 heads, l = q.k + bias (K coalesced, consumed in 8-float
//       chunks), e = exp(l); per-row wave-partials of S -> LDS; e kept
//       across heads packed bf16x2 (16 VGPRs).
//   P2: 32 threads fold S partials -> srcp[h][r].
//   P3: A_c[r] = sum_h e*srcp*vw_c; apply staged delta + mask; 12 block
//       butterflies; 12 threads write out.
// No P' materialization: saves 33.6 MB of HBM round-trip vs split design.
// ---------------------------------------------------------------------------
__global__ __launch_bounds__(512) void attn_fused_kernel(
    const float* __restrict__ Q, const float* __restrict__ Kt,
    const float* __restrict__ attn_bias, const float* __restrict__ vw,
    const float* __restrict__ delta_pos,
    const int* __restrict__ drop_edge_mask, const int* __restrict__ drop_or_add,
    const float* __restrict__ bf1, const float* __restrict__ bf2,
    const float* __restrict__ bf3, float* __restrict__ out)
{
    const int blk = blockIdx.x;                // 512 blocks
    const int b = blk >> 7;
    const int n0 = (blk & 127) * RR;
    const int m = threadIdx.x;                 // column m
    const int wv = m >> 6, ln = m & 63;

    __shared__ float sdp[RR * 3 * NN];         // 24 KB staged delta rows
    __shared__ float red[HH][RR][8];           // 1 KB S wave-partials
    __shared__ float srcp[HH][RR];
    __shared__ float r3[RR][3][8];

    // coalesced stage of 4 contiguous delta rows (6144 floats)
    {
        const float* dpb = delta_pos + (size_t)(b * NN + n0) * NN * 3;
        #pragma unroll
        for (int i = 0; i < RR * 3; ++i)
            sdp[i * 512 + m] = dpb[i * 512 + m];
    }

    unsigned int ep[HH][RR / 2];               // bf16x2-packed e, 16 VGPRs

    #pragma unroll
    for (int h = 0; h < HH; ++h) {
        const float* kp = Kt + ((size_t)(b * HH + h) * DD) * NN + m;
        const size_t bias_base = ((size_t)(b * HH + h) * NN + n0) * NN + m;
        const float* qb = Q + (b * NN + n0) * EE + h * DD;  // block-uniform

        float l[RR];
        #pragma unroll
        for (int r = 0; r < RR; ++r)
            l[r] = attn_bias[bias_base + (size_t)r * NN];

        #pragma unroll
        for (int dc = 0; dc < DD; dc += 8) {
            float k8[8];
            #pragma unroll
            for (int i = 0; i < 8; ++i)
                k8[i] = kp[(size_t)(dc + i) * NN];
            #pragma unroll
            for (int i = 0; i < 8; ++i) {
                #pragma unroll
                for (int r = 0; r < RR; ++r)
                    l[r] += qb[r * EE + dc + i] * k8[i];
            }
        }

        float e[RR];
        #pragma unroll
        for (int r = 0; r < RR; ++r)
            e[r] = __expf(l[r]);               // |l| ~ 10 << 88: safe

        #pragma unroll
        for (int r = 0; r < RR; ++r) {
            float x = e[r];
            #pragma unroll
            for (int off = 32; off; off >>= 1)
                x += __shfl_xor(x, off, 64);
            if (ln == 0) red[h][r][wv] = x;    // S partials stay f32-exact
        }

        #pragma unroll
        for (int rp = 0; rp < RR / 2; ++rp) {  // RNE bf16 pack
            const unsigned int u0 =
                (unsigned int)__bfloat16_as_ushort(__float2bfloat16(e[2 * rp]));
            const unsigned int u1 =
                (unsigned int)__bfloat16_as_ushort(__float2bfloat16(e[2 * rp + 1]));
            ep[h][rp] = u0 | (u1 << 16);
        }
    }
    __syncthreads();

    if (m < HH * RR) {                         // 32 threads: (h, r)
        const int h = m >> 2, r = m & 3;
        float s = 0.f;
        #pragma unroll
        for (int w = 0; w < 8; ++w) s += red[h][r][w];
        srcp[h][r] = __builtin_amdgcn_rcpf(s);
    }
    __syncthreads();

    float A0[RR], A1[RR], A2[RR];
    #pragma unroll
    for (int r = 0; r < RR; ++r) { A0[r] = 0.f; A1[r] = 0.f; A2[r] = 0.f; }

    #pragma unroll
    for (int h = 0; h < HH; ++h) {
        const float* vwp = vw + (b * HH + h) * 3 * NN + m;
        const float vw0 = vwp[0], vw1 = vwp[NN], vw2 = vwp[2 * NN];
        #pragma unroll
        for (int rp = 0; rp < RR / 2; ++rp) {
            const unsigned int u = ep[h][rp];
            const float e0 = __uint_as_float(u << 16) * srcp[h][2 * rp];
            const float e1 = __uint_as_float(u & 0xffff0000u) * srcp[h][2 * rp + 1];
            A0[2 * rp] += e0 * vw0;  A0[2 * rp + 1] += e1 * vw0;
            A1[2 * rp] += e0 * vw1;  A1[2 * rp + 1] += e1 * vw1;
            A2[2 * rp] += e0 * vw2;  A2[2 * rp + 1] += e1 * vw2;
        }
    }

    const int doa = drop_or_add[0];
    #pragma unroll
    for (int r = 0; r < RR; ++r) {
        const float mk =
            (doa != 0 && drop_edge_mask[(n0 + r) * NN + m] != 0) ? 0.f : 1.f;
        const float* dp = &sdp[r * 3 * NN + 3 * m];
        float v0 = A0[r] * dp[0] * mk;
        float v1 = A1[r] * dp[1] * mk;
        float v2 = A2[r] * dp[2] * mk;
        #pragma unroll
        for (int off = 32; off; off >>= 1) {
            v0 += __shfl_xor(v0, off, 64);
            v1 += __shfl_xor(v1, off, 64);
            v2 += __shfl_xor(v2, off, 64);
        }
        if (ln == 0) {
            r3[r][0][wv] = v0; r3[r][1][wv] = v1; r3[r][2][wv] = v2;
        }
    }
    __syncthreads();

    if (m < RR * 3) {                          // 12 threads
        const int r = m / 3, c = m % 3;
        float s = 0.f;
        #pragma unroll
        for (int w = 0; w < 8; ++w) s += r3[r][c][w];
        const float bias = (c == 0) ? bf1[0] : (c == 1) ? bf2[0] : bf3[0];
        out[(b * NN + n0 + r) * 3 + c] = s + bias;
    }
}

// ---------------------------------------------------------------------------
extern "C" void kernel_launch(void* const* d_in, const int* in_sizes, int n_in,
                              void* d_out, int out_size, void* d_ws, size_t ws_size,
                              hipStream_t stream)
{
    const float* query          = (const float*)d_in[0];
    const float* attn_bias      = (const float*)d_in[1];
    const float* delta_pos      = (const float*)d_in[2];
    const int*   drop_edge_mask = (const int*)d_in[3];
    const float* Wq  = (const float*)d_in[4];
    const float* bq  = (const float*)d_in[5];
    const float* Wk  = (const float*)d_in[6];
    const float* bk  = (const float*)d_in[7];
    const float* Wv  = (const float*)d_in[8];
    const float* bv  = (const float*)d_in[9];
    const float* Wf1 = (const float*)d_in[10];
    const float* bf1 = (const float*)d_in[11];
    const float* Wf2 = (const float*)d_in[12];
    const float* bf2 = (const float*)d_in[13];
    const float* Wf3 = (const float*)d_in[14];
    const float* bf3 = (const float*)d_in[15];
    const int*   drop_or_add = (const int*)d_in[16];

    float* ws = (float*)d_ws;
    float* Q   = ws;                 // 524288 floats
    float* Kt  = ws + 524288;        // 524288 floats
    float* vw  = ws + 1048576;       // 49152 floats

    proj_kernel<<<dim3(BB * NN / PR, 3), 256, 0, stream>>>(
        query, Wq, bq, Wk, bk, Wv, bv, Wf1, Wf2, Wf3, Q, Kt, vw);
    attn_fused_kernel<<<BB * NN / RR, 512, 0, stream>>>(
        Q, Kt, attn_bias, vw, delta_pos, drop_edge_mask, drop_or_add,
        bf1, bf2, bf3, (float*)d_out);
}